// Round 5
// baseline (22.435 us; speedup 1.0000x reference)
//
#include <hip/hip_runtime.h>
#include <math.h>

#define NQ 10
#define NDEPTH 4
#define NR 16              // amplitudes per lane (2^4)

// One WAVE per batch element: 64 lanes x 16 complex amps = 1024 amplitudes.
// Flat index i = lane*16 + r. Qubit q <-> bit k = 9-q of i:
//   q 0..5  -> lane bit (5-q), xor mask M = 32 >> q
//   q 6..9  -> register bit (9-q)
// xor-1/2/8 via DPP (VALU), xor-16/32 via v_permlane{16,32}_swap_b32 (VALU),
// xor-4 via ds_swizzle, composed CNOT chain via ds_bpermute.
// All DS gates are BATCH-issued (temps first, consume after) so each gate
// pays ONE lgkmcnt latency instead of 32.

typedef int v2i __attribute__((ext_vector_type(2)));

__device__ __forceinline__ float xf(int i) { return __int_as_float(i); }
__device__ __forceinline__ int   fx(float f) { return __float_as_int(f); }

template<int M>
__device__ __forceinline__ float lane_xor(float v, int lane) {
    if constexpr (M == 1)        // quad_perm [1,0,3,2]
        return xf(__builtin_amdgcn_update_dpp(fx(v), fx(v), 0xB1, 0xF, 0xF, true));
    else if constexpr (M == 2)   // quad_perm [2,3,0,1]
        return xf(__builtin_amdgcn_update_dpp(fx(v), fx(v), 0x4E, 0xF, 0xF, true));
    else if constexpr (M == 8)   // row_ror:8 == xor 8 within 16-lane row
        return xf(__builtin_amdgcn_update_dpp(fx(v), fx(v), 0x128, 0xF, 0xF, true));
    else if constexpr (M == 4)   // ds_swizzle bit-mode xor 4
        return xf(__builtin_amdgcn_ds_swizzle(fx(v), 0x101F));
    else if constexpr (M == 16) {
#if __has_builtin(__builtin_amdgcn_permlane16_swap)
        // D=S=v: p[0][i]=v[i&~16], p[1][i]=v[i|16] -> xor16 = (lane&16)?p0:p1
        v2i p = __builtin_amdgcn_permlane16_swap(fx(v), fx(v), false, false);
        return (lane & 16) ? xf(p[0]) : xf(p[1]);
#else
        return xf(__builtin_amdgcn_ds_swizzle(fx(v), 0x401F));
#endif
    } else {                     // M == 32
#if __has_builtin(__builtin_amdgcn_permlane32_swap)
        // D=S=v: p[0][i]=v[i&31], p[1][i]=v[i|32] -> xor32 = (lane&32)?p0:p1
        v2i p = __builtin_amdgcn_permlane32_swap(fx(v), fx(v), false, false);
        return (lane & 32) ? xf(p[0]) : xf(p[1]);
#else
        return xf(__builtin_amdgcn_ds_bpermute((lane ^ 32) << 2, fx(v)));
#endif
    }
}

template<int M>
__device__ __forceinline__ void rx_lanebit(float (&re)[NR], float (&im)[NR],
                                           float c, float s, int lane) {
    float pre[NR], pim[NR];
    #pragma unroll
    for (int r = 0; r < NR; ++r) {
        pre[r] = lane_xor<M>(re[r], lane);
        pim[r] = lane_xor<M>(im[r], lane);
    }
    #pragma unroll
    for (int r = 0; r < NR; ++r) {
        re[r] = c * re[r] + s * pim[r];
        im[r] = c * im[r] - s * pre[r];
    }
}

template<int J>
__device__ __forceinline__ void rx_regbit(float (&re)[NR], float (&im)[NR],
                                          float c, float s) {
    #pragma unroll
    for (int r0 = 0; r0 < NR; ++r0) {
        if (r0 & (1 << J)) continue;
        const int r1 = r0 | (1 << J);
        const float R0 = re[r0], M0 = im[r0];
        const float R1 = re[r1], M1 = im[r1];
        re[r0] = c * R0 + s * M1;
        im[r0] = c * M0 - s * R1;
        re[r1] = c * R1 + s * M0;
        im[r1] = c * M1 - s * R0;
    }
}

__device__ __forceinline__ void cnot_ring(float (&re)[NR], float (&im)[NR],
                                          int lane, int jaddr) {
    // CNOTs (0->1)...(4->5): composed lane permutation, BATCHED bpermute
    float tre[NR], tim[NR];
    #pragma unroll
    for (int r = 0; r < NR; ++r) {
        tre[r] = xf(__builtin_amdgcn_ds_bpermute(jaddr, fx(re[r])));
        tim[r] = xf(__builtin_amdgcn_ds_bpermute(jaddr, fx(im[r])));
    }
    // C(5->6): ctrl lane bit0, tgt reg bit3 -> conditional reg swap (from temps)
    const bool ctl = (lane & 1) != 0;
    #pragma unroll
    for (int r = 0; r < 8; ++r) {
        const float a0 = tre[r], a1 = tre[r + 8];
        re[r] = ctl ? a1 : a0;  re[r + 8] = ctl ? a0 : a1;
        const float b0 = tim[r], b1 = tim[r + 8];
        im[r] = ctl ? b1 : b0;  im[r + 8] = ctl ? b0 : b1;
    }
    // C(6->7): regs bit3=1 swap bit2
    #pragma unroll
    for (int r = 8; r < 12; ++r) {
        float t = re[r]; re[r] = re[r + 4]; re[r + 4] = t;
        t = im[r]; im[r] = im[r + 4]; im[r + 4] = t;
    }
    // C(7->8): regs bit2=1 swap bit1
    {
        const int rs[4] = {4, 5, 12, 13};
        #pragma unroll
        for (int k = 0; k < 4; ++k) {
            const int r = rs[k];
            float t = re[r]; re[r] = re[r + 2]; re[r + 2] = t;
            t = im[r]; im[r] = im[r + 2]; im[r + 2] = t;
        }
    }
    // C(8->9): regs bit1=1 swap bit0
    {
        const int rs[4] = {2, 6, 10, 14};
        #pragma unroll
        for (int k = 0; k < 4; ++k) {
            const int r = rs[k];
            float t = re[r]; re[r] = re[r + 1]; re[r + 1] = t;
            t = im[r]; im[r] = im[r + 1]; im[r + 1] = t;
        }
    }
    // C(9->0): ctrl reg bit0, tgt lane mask 32 -> permlane32 xor (VALU)
    #pragma unroll
    for (int r = 1; r < NR; r += 2) {
        re[r] = lane_xor<32>(re[r], lane);
        im[r] = lane_xor<32>(im[r], lane);
    }
}

__global__ __launch_bounds__(256, 2) void vql_kernel(
    const float* __restrict__ x,     // (B, NQ)
    const float* __restrict__ w,     // (NDEPTH, NQ)
    float* __restrict__ out,         // (B, NQ)
    int B)
{
    const int lane = threadIdx.x & 63;
    const int b = blockIdx.x * 4 + (threadIdx.x >> 6);
    if (b >= B) return;

    // composed CNOT(0->1..4->5) source lane (hoisted)
    int j = lane;
    j ^= ((j >> 1) & 1);
    j ^= ((j >> 2) & 1) << 1;
    j ^= ((j >> 3) & 1) << 2;
    j ^= ((j >> 4) & 1) << 3;
    j ^= ((j >> 5) & 1) << 4;
    const int jaddr = j << 2;

    // ---- preload per-batch angles (vectorized, one latency) ----
    const float2* xr = reinterpret_cast<const float2*>(x + b * NQ);  // 8B aligned
    const float2 x01 = xr[0], x23 = xr[1], x45 = xr[2], x67 = xr[3], x89 = xr[4];
    const float xa[NQ] = {0.5f * x01.x, 0.5f * x01.y, 0.5f * x23.x, 0.5f * x23.y,
                          0.5f * x45.x, 0.5f * x45.y, 0.5f * x67.x, 0.5f * x67.y,
                          0.5f * x89.x, 0.5f * x89.y};

    // ---- hoist ALL sincos (layer0 folded into init; layers 1..3 stored) ----
    float lc[NDEPTH - 1][NQ], ls[NDEPTH - 1][NQ];
    #pragma unroll
    for (int l = 1; l < NDEPTH; ++l)
        #pragma unroll
        for (int q = 0; q < NQ; ++q)
            __sincosf(0.5f * w[l * NQ + q], &ls[l - 1][q], &lc[l - 1][q]);

    // ---- analytic product state: amp = prod_q (RX(w0q) RY(xq) |0>) ----
    float v0r[NQ], v0i[NQ], v1r[NQ], v1i[NQ];
    #pragma unroll
    for (int q = 0; q < NQ; ++q) {
        float sy, cy, s, c;
        __sincosf(xa[q], &sy, &cy);
        __sincosf(0.5f * w[q], &s, &c);   // layer-0 weights
        v0r[q] = c * cy;  v0i[q] = -s * sy;
        v1r[q] = c * sy;  v1i[q] = -s * cy;
    }
    // lane factor: qubits 0..5, qubit q <-> lane bit (5-q)
    float Pr = 1.f, Pi = 0.f;
    #pragma unroll
    for (int q = 0; q < 6; ++q) {
        const int bit = (lane >> (5 - q)) & 1;
        const float ar = bit ? v1r[q] : v0r[q];
        const float ai = bit ? v1i[q] : v0i[q];
        const float nr = Pr * ar - Pi * ai;
        const float ni = Pr * ai + Pi * ar;
        Pr = nr; Pi = ni;
    }
    // reg factors: r bit3 = qubit6, bit2 = qubit7, bit1 = qubit8, bit0 = qubit9
    float hr[4], hi4[4], gr[4], gi4[4];
    #pragma unroll
    for (int t2 = 0; t2 < 4; ++t2) {
        const int bA = (t2 >> 1) & 1, bB = t2 & 1;
        {   // qubits 6,7
            const float ar = bA ? v1r[6] : v0r[6], ai = bA ? v1i[6] : v0i[6];
            const float br = bB ? v1r[7] : v0r[7], bi = bB ? v1i[7] : v0i[7];
            hr[t2] = ar * br - ai * bi;
            hi4[t2] = ar * bi + ai * br;
        }
        {   // qubits 8,9
            const float ar = bA ? v1r[8] : v0r[8], ai = bA ? v1i[8] : v0i[8];
            const float br = bB ? v1r[9] : v0r[9], bi = bB ? v1i[9] : v0i[9];
            gr[t2] = ar * br - ai * bi;
            gi4[t2] = ar * bi + ai * br;
        }
    }
    float re[NR], im[NR];
    #pragma unroll
    for (int r = 0; r < NR; ++r) {
        const float ar = hr[(r >> 2) & 3], ai = hi4[(r >> 2) & 3];
        const float br = gr[r & 3],        bi = gi4[r & 3];
        const float qr = ar * br - ai * bi;
        const float qi = ar * bi + ai * br;
        re[r] = Pr * qr - Pi * qi;
        im[r] = Pr * qi + Pi * qr;
    }

    // ---- layer 0 CNOT ring (RX layer 0 folded into init) ----
    cnot_ring(re, im, lane, jaddr);

    // ---- layers 1..3: RX all qubits + CNOT ring ----
    #pragma unroll
    for (int l = 1; l < NDEPTH; ++l) {
        const float* c = lc[l - 1];
        const float* s = ls[l - 1];
        rx_lanebit<32>(re, im, c[0], s[0], lane);
        rx_lanebit<16>(re, im, c[1], s[1], lane);
        rx_lanebit< 8>(re, im, c[2], s[2], lane);
        rx_lanebit< 4>(re, im, c[3], s[3], lane);
        rx_lanebit< 2>(re, im, c[4], s[4], lane);
        rx_lanebit< 1>(re, im, c[5], s[5], lane);
        rx_regbit<3>(re, im, c[6], s[6]);
        rx_regbit<2>(re, im, c[7], s[7]);
        rx_regbit<1>(re, im, c[8], s[8]);
        rx_regbit<0>(re, im, c[9], s[9]);
        cnot_ring(re, im, lane, jaddr);
    }

    // ---- readout ----
    float p[NR];
    #pragma unroll
    for (int r = 0; r < NR; ++r) p[r] = re[r] * re[r] + im[r] * im[r];

    float ptot = 0.f, z6 = 0.f, z7 = 0.f, z8 = 0.f, z9 = 0.f;
    #pragma unroll
    for (int r = 0; r < NR; ++r) {
        ptot += p[r];
        z6 += (r & 8) ? -p[r] : p[r];
        z7 += (r & 4) ? -p[r] : p[r];
        z8 += (r & 2) ? -p[r] : p[r];
        z9 += (r & 1) ? -p[r] : p[r];
    }
    float z[NQ];
    z[0] = (lane & 32) ? -ptot : ptot;
    z[1] = (lane & 16) ? -ptot : ptot;
    z[2] = (lane &  8) ? -ptot : ptot;
    z[3] = (lane &  4) ? -ptot : ptot;
    z[4] = (lane &  2) ? -ptot : ptot;
    z[5] = (lane &  1) ? -ptot : ptot;
    z[6] = z6; z[7] = z7; z[8] = z8; z[9] = z9;

    #pragma unroll
    for (int q = 0; q < NQ; ++q) {
        z[q] += lane_xor<1>(z[q], lane);
        z[q] += lane_xor<2>(z[q], lane);
        z[q] += lane_xor<4>(z[q], lane);
        z[q] += lane_xor<8>(z[q], lane);
        z[q] += lane_xor<16>(z[q], lane);
        z[q] += lane_xor<32>(z[q], lane);
    }
    if (lane == 0) {
        #pragma unroll
        for (int q = 0; q < NQ; ++q) out[b * NQ + q] = z[q];
    }
}

extern "C" void kernel_launch(void* const* d_in, const int* in_sizes, int n_in,
                              void* d_out, int out_size, void* d_ws, size_t ws_size,
                              hipStream_t stream) {
    const float* x = (const float*)d_in[0];        // (BATCH, NQ) fp32
    const float* w = (const float*)d_in[1];        // (NDEPTH, NQ) fp32
    float* out = (float*)d_out;                    // (BATCH, NQ) fp32
    const int B = in_sizes[0] / NQ;
    vql_kernel<<<(B + 3) / 4, 256, 0, stream>>>(x, w, out, B);
}

// Round 6
// 21.083 us; speedup vs baseline: 1.0642x; 1.0642x over previous
//
#include <hip/hip_runtime.h>
#include <math.h>

#define NQ 10
#define NDEPTH 4
#define NR 8               // amplitudes per lane (2^3)

// TWO WAVES per batch element (block = 128 threads = 1 element).
// Flat amp index i = wave*512 + lane*8 + r. Qubit q <-> bit (9-q) of i:
//   qubit 0      -> wave bit           (LDS exchange, 2x/layer max)
//   qubits 1..6  -> lane bits 5..0     (xor mask 64>>q)
//   qubits 7..9  -> reg bits 2..0
// xor-1/2/8 via DPP, xor-4/16 via ds_swizzle, xor-32 + composed CNOT chain
// via ds_bpermute (round-4 proven implementations).

__device__ __forceinline__ float xf(int i) { return __int_as_float(i); }
__device__ __forceinline__ int   fx(float f) { return __float_as_int(f); }

template<int M>
__device__ __forceinline__ float lane_xor(float v, int addr32) {
    if constexpr (M == 1)        // quad_perm [1,0,3,2]
        return xf(__builtin_amdgcn_update_dpp(fx(v), fx(v), 0xB1, 0xF, 0xF, true));
    else if constexpr (M == 2)   // quad_perm [2,3,0,1]
        return xf(__builtin_amdgcn_update_dpp(fx(v), fx(v), 0x4E, 0xF, 0xF, true));
    else if constexpr (M == 8)   // row_ror:8
        return xf(__builtin_amdgcn_update_dpp(fx(v), fx(v), 0x128, 0xF, 0xF, true));
    else if constexpr (M == 4)
        return xf(__builtin_amdgcn_ds_swizzle(fx(v), 0x101F));
    else if constexpr (M == 16)
        return xf(__builtin_amdgcn_ds_swizzle(fx(v), 0x401F));
    else                         // M == 32
        return xf(__builtin_amdgcn_ds_bpermute(addr32, fx(v)));
}

template<int M>
__device__ __forceinline__ void rx_lanebit(float (&re)[NR], float (&im)[NR],
                                           float c, float s, int addr32) {
    #pragma unroll
    for (int r = 0; r < NR; ++r) {
        const float pre = lane_xor<M>(re[r], addr32);
        const float pim = lane_xor<M>(im[r], addr32);
        re[r] = c * re[r] + s * pim;
        im[r] = c * im[r] - s * pre;
    }
}

template<int J>
__device__ __forceinline__ void rx_regbit(float (&re)[NR], float (&im)[NR],
                                          float c, float s) {
    #pragma unroll
    for (int r0 = 0; r0 < NR; ++r0) {
        if (r0 & (1 << J)) continue;
        const int r1 = r0 | (1 << J);
        const float R0 = re[r0], M0 = im[r0];
        const float R1 = re[r1], M1 = im[r1];
        re[r0] = c * R0 + s * M1;
        im[r0] = c * M0 - s * R1;
        re[r1] = c * R1 + s * M0;
        im[r1] = c * M1 - s * R0;
    }
}

// RX on qubit 0 (wave bit): full cross-wave exchange through LDS.
__device__ __forceinline__ void rx_wavebit(float (&re)[NR], float (&im)[NR],
                                           float c, float s, int wv, int lane,
                                           float4 (*buf)[4][64]) {
    buf[wv][0][lane] = make_float4(re[0], re[1], re[2], re[3]);
    buf[wv][1][lane] = make_float4(re[4], re[5], re[6], re[7]);
    buf[wv][2][lane] = make_float4(im[0], im[1], im[2], im[3]);
    buf[wv][3][lane] = make_float4(im[4], im[5], im[6], im[7]);
    __syncthreads();
    const float4 pr0 = buf[wv ^ 1][0][lane], pr1 = buf[wv ^ 1][1][lane];
    const float4 pi0 = buf[wv ^ 1][2][lane], pi1 = buf[wv ^ 1][3][lane];
    const float pre[NR] = {pr0.x, pr0.y, pr0.z, pr0.w, pr1.x, pr1.y, pr1.z, pr1.w};
    const float pim[NR] = {pi0.x, pi0.y, pi0.z, pi0.w, pi1.x, pi1.y, pi1.z, pi1.w};
    #pragma unroll
    for (int r = 0; r < NR; ++r) {
        re[r] = c * re[r] + s * pim[r];
        im[r] = c * im[r] - s * pre[r];
    }
}

__device__ __forceinline__ void cnot_ring(float (&re)[NR], float (&im)[NR],
                                          int wv, int lane, int jaddr, int addr32,
                                          float4 (*buf)[4][64]) {
    // C(0->1): ctrl = wave bit -> wave 1 flips lane bit5 (xor 32), wave 0 idle
    if (wv == 1) {
        #pragma unroll
        for (int r = 0; r < NR; ++r) {
            re[r] = lane_xor<32>(re[r], addr32);
            im[r] = lane_xor<32>(im[r], addr32);
        }
    }
    // C(1->2)..C(5->6): composed lane permutation, one bpermute pass
    #pragma unroll
    for (int r = 0; r < NR; ++r) {
        re[r] = xf(__builtin_amdgcn_ds_bpermute(jaddr, fx(re[r])));
        im[r] = xf(__builtin_amdgcn_ds_bpermute(jaddr, fx(im[r])));
    }
    // C(6->7): ctrl lane bit0 -> swap reg bit2
    const bool ctl = (lane & 1) != 0;
    #pragma unroll
    for (int r = 0; r < 4; ++r) {
        const float a0 = re[r], a1 = re[r + 4];
        re[r] = ctl ? a1 : a0;  re[r + 4] = ctl ? a0 : a1;
        const float b0 = im[r], b1 = im[r + 4];
        im[r] = ctl ? b1 : b0;  im[r + 4] = ctl ? b0 : b1;
    }
    // C(7->8): regs bit2=1 swap bit1 -> (4,6),(5,7)
    {
        float t;
        t = re[4]; re[4] = re[6]; re[6] = t;  t = im[4]; im[4] = im[6]; im[6] = t;
        t = re[5]; re[5] = re[7]; re[7] = t;  t = im[5]; im[5] = im[7]; im[7] = t;
    }
    // C(8->9): regs bit1=1 swap bit0 -> (2,3),(6,7)
    {
        float t;
        t = re[2]; re[2] = re[3]; re[3] = t;  t = im[2]; im[2] = im[3]; im[3] = t;
        t = re[6]; re[6] = re[7]; re[7] = t;  t = im[6]; im[6] = im[7]; im[7] = t;
    }
    // C(9->0): ctrl reg bit0 -> flip wave bit: odd regs swap across waves
    buf[wv][0][lane] = make_float4(re[1], re[3], re[5], re[7]);
    buf[wv][1][lane] = make_float4(im[1], im[3], im[5], im[7]);
    __syncthreads();
    const float4 qr = buf[wv ^ 1][0][lane];
    const float4 qi = buf[wv ^ 1][1][lane];
    re[1] = qr.x; re[3] = qr.y; re[5] = qr.z; re[7] = qr.w;
    im[1] = qi.x; im[3] = qi.y; im[5] = qi.z; im[7] = qi.w;
}

__global__ __launch_bounds__(128, 4) void vql_kernel(
    const float* __restrict__ x,     // (B, NQ)
    const float* __restrict__ w,     // (NDEPTH, NQ)
    float* __restrict__ out)         // (B, NQ)
{
    __shared__ float4 bufA[2][4][64];   // 8 KB, double-buffered exchanges
    __shared__ float4 bufB[2][4][64];   // 8 KB
    __shared__ float  zbuf[2][NQ];

    const int lane = threadIdx.x & 63;
    const int wv   = threadIdx.x >> 6;
    const int b    = blockIdx.x;

    // hoisted cross-lane addresses
    const int addr32 = (lane ^ 32) << 2;
    int j = lane;                       // composed C(1->2)..C(5->6) source lane
    j ^= ((j >> 1) & 1);
    j ^= ((j >> 2) & 1) << 1;
    j ^= ((j >> 3) & 1) << 2;
    j ^= ((j >> 4) & 1) << 3;
    j ^= ((j >> 5) & 1) << 4;
    const int jaddr = j << 2;

    // ---- per-batch angles (vectorized) ----
    const float2* xr = reinterpret_cast<const float2*>(x + b * NQ);
    const float2 x01 = xr[0], x23 = xr[1], x45 = xr[2], x67 = xr[3], x89 = xr[4];
    const float xa[NQ] = {0.5f * x01.x, 0.5f * x01.y, 0.5f * x23.x, 0.5f * x23.y,
                          0.5f * x45.x, 0.5f * x45.y, 0.5f * x67.x, 0.5f * x67.y,
                          0.5f * x89.x, 0.5f * x89.y};

    // ---- analytic product state: amp = prod_q (RX(w0q) RY(xq) |0>) ----
    float v0r[NQ], v0i[NQ], v1r[NQ], v1i[NQ];
    #pragma unroll
    for (int q = 0; q < NQ; ++q) {
        float sy, cy, s, c;
        __sincosf(xa[q], &sy, &cy);
        __sincosf(0.5f * w[q], &s, &c);   // layer-0 weights
        v0r[q] = c * cy;  v0i[q] = -s * sy;
        v1r[q] = c * sy;  v1i[q] = -s * cy;
    }
    // wave factor (qubit 0) then lane factors (qubits 1..6, lane bit 6-q)
    float Pr = wv ? v1r[0] : v0r[0];
    float Pi = wv ? v1i[0] : v0i[0];
    #pragma unroll
    for (int q = 1; q <= 6; ++q) {
        const int bit = (lane >> (6 - q)) & 1;
        const float ar = bit ? v1r[q] : v0r[q];
        const float ai = bit ? v1i[q] : v0i[q];
        const float nr = Pr * ar - Pi * ai;
        const float ni = Pr * ai + Pi * ar;
        Pr = nr; Pi = ni;
    }
    // reg factors: r = q7*4 + q8*2 + q9
    float hr[4], hi4[4];            // qubits 7,8 combos
    #pragma unroll
    for (int t2 = 0; t2 < 4; ++t2) {
        const int bA = (t2 >> 1) & 1, bB = t2 & 1;
        const float ar = bA ? v1r[7] : v0r[7], ai = bA ? v1i[7] : v0i[7];
        const float br = bB ? v1r[8] : v0r[8], bi = bB ? v1i[8] : v0i[8];
        hr[t2]  = ar * br - ai * bi;
        hi4[t2] = ar * bi + ai * br;
    }
    float re[NR], im[NR];
    #pragma unroll
    for (int r = 0; r < NR; ++r) {
        const float ar = hr[r >> 1], ai = hi4[r >> 1];
        const float br = (r & 1) ? v1r[9] : v0r[9];
        const float bi = (r & 1) ? v1i[9] : v0i[9];
        const float qr = ar * br - ai * bi;
        const float qi = ar * bi + ai * br;
        re[r] = Pr * qr - Pi * qi;
        im[r] = Pr * qi + Pi * qr;
    }

    // ---- layer 0 ring (RX layer 0 folded into init) ----
    cnot_ring(re, im, wv, lane, jaddr, addr32, bufA);

    // ---- layers 1..3: RX all qubits + ring ----
    #pragma unroll
    for (int l = 1; l < NDEPTH; ++l) {
        float c[NQ], s[NQ];
        #pragma unroll
        for (int q = 0; q < NQ; ++q)
            __sincosf(0.5f * w[l * NQ + q], &s[q], &c[q]);
        rx_wavebit(re, im, c[0], s[0], wv, lane, bufB);     // qubit 0
        rx_lanebit<32>(re, im, c[1], s[1], addr32);
        rx_lanebit<16>(re, im, c[2], s[2], addr32);
        rx_lanebit< 8>(re, im, c[3], s[3], addr32);
        rx_lanebit< 4>(re, im, c[4], s[4], addr32);
        rx_lanebit< 2>(re, im, c[5], s[5], addr32);
        rx_lanebit< 1>(re, im, c[6], s[6], addr32);
        rx_regbit<2>(re, im, c[7], s[7]);
        rx_regbit<1>(re, im, c[8], s[8]);
        rx_regbit<0>(re, im, c[9], s[9]);
        cnot_ring(re, im, wv, lane, jaddr, addr32, bufA);
    }

    // ---- readout ----
    float p[NR];
    #pragma unroll
    for (int r = 0; r < NR; ++r) p[r] = re[r] * re[r] + im[r] * im[r];

    float ptot = 0.f, z7 = 0.f, z8 = 0.f, z9 = 0.f;
    #pragma unroll
    for (int r = 0; r < NR; ++r) {
        ptot += p[r];
        z7 += (r & 4) ? -p[r] : p[r];
        z8 += (r & 2) ? -p[r] : p[r];
        z9 += (r & 1) ? -p[r] : p[r];
    }
    float z[NQ];
    z[0] = wv ? -ptot : ptot;
    z[1] = (lane & 32) ? -ptot : ptot;
    z[2] = (lane & 16) ? -ptot : ptot;
    z[3] = (lane &  8) ? -ptot : ptot;
    z[4] = (lane &  4) ? -ptot : ptot;
    z[5] = (lane &  2) ? -ptot : ptot;
    z[6] = (lane &  1) ? -ptot : ptot;
    z[7] = z7; z[8] = z8; z[9] = z9;

    #pragma unroll
    for (int q = 0; q < NQ; ++q) {
        z[q] += lane_xor<1>(z[q], addr32);
        z[q] += lane_xor<2>(z[q], addr32);
        z[q] += lane_xor<4>(z[q], addr32);
        z[q] += lane_xor<8>(z[q], addr32);
        z[q] += lane_xor<16>(z[q], addr32);
        z[q] += lane_xor<32>(z[q], addr32);
    }
    if (lane == 0) {
        #pragma unroll
        for (int q = 0; q < NQ; ++q) zbuf[wv][q] = z[q];
    }
    __syncthreads();
    if (wv == 0 && lane == 0) {
        #pragma unroll
        for (int q = 0; q < NQ; ++q) out[b * NQ + q] = z[q] + zbuf[1][q];
    }
}

extern "C" void kernel_launch(void* const* d_in, const int* in_sizes, int n_in,
                              void* d_out, int out_size, void* d_ws, size_t ws_size,
                              hipStream_t stream) {
    const float* x = (const float*)d_in[0];        // (BATCH, NQ) fp32
    const float* w = (const float*)d_in[1];        // (NDEPTH, NQ) fp32
    float* out = (float*)d_out;                    // (BATCH, NQ) fp32
    const int B = in_sizes[0] / NQ;
    vql_kernel<<<B, 128, 0, stream>>>(x, w, out);
}

// Round 7
// 19.064 us; speedup vs baseline: 1.1768x; 1.1059x over previous
//
#include <hip/hip_runtime.h>
#include <math.h>

#define NQ 10
#define NDEPTH 4
#define NR 16              // amplitudes per lane (2^4)

// One WAVE per batch element: 64 lanes x 16 complex amps = 1024 amplitudes.
// Flat index i = lane*16 + r. Qubit q <-> bit k = 9-q of i:
//   q 0..5  -> lane bit (5-q), xor mask M = 32 >> q
//   q 6..9  -> register bit (9-q)
// Exact-math restructuring:
//  * ring-0 folded into the analytic product-state init via the index map
//    j(i) = (i ^ (i>>1)) ^ ((i&1)*0x300)  (ring is GF(2)-linear on indices)
//  * ring-3 removed by pushing Z_q through the CNOTs:
//    <Z_0> -> <Z_1..Z_9>,  <Z_q> -> <Z_0..Z_q> (q>=1): parity-mask readout.
// Gates: xor-1/2/8 via DPP, xor-4/16 via ds_swizzle, xor-32 + composed
// lane-CNOT chain via ds_bpermute (round-4 proven implementations).

__device__ __forceinline__ float xf(int i) { return __int_as_float(i); }
__device__ __forceinline__ int   fx(float f) { return __float_as_int(f); }

template<int M>
__device__ __forceinline__ float lane_xor(float v, int addr32) {
    if constexpr (M == 1)        // quad_perm [1,0,3,2]
        return xf(__builtin_amdgcn_update_dpp(fx(v), fx(v), 0xB1, 0xF, 0xF, true));
    else if constexpr (M == 2)   // quad_perm [2,3,0,1]
        return xf(__builtin_amdgcn_update_dpp(fx(v), fx(v), 0x4E, 0xF, 0xF, true));
    else if constexpr (M == 8)   // row_ror:8
        return xf(__builtin_amdgcn_update_dpp(fx(v), fx(v), 0x128, 0xF, 0xF, true));
    else if constexpr (M == 4)   // ds_swizzle bit-mode xor 4
        return xf(__builtin_amdgcn_ds_swizzle(fx(v), 0x101F));
    else if constexpr (M == 16)  // ds_swizzle bit-mode xor 16
        return xf(__builtin_amdgcn_ds_swizzle(fx(v), 0x401F));
    else                         // M == 32: bpermute, addr32 = (lane^32)<<2
        return xf(__builtin_amdgcn_ds_bpermute(addr32, fx(v)));
}

template<int M>
__device__ __forceinline__ void rx_lanebit(float (&re)[NR], float (&im)[NR],
                                           float c, float s, int addr32) {
    #pragma unroll
    for (int r = 0; r < NR; ++r) {
        const float pre = lane_xor<M>(re[r], addr32);
        const float pim = lane_xor<M>(im[r], addr32);
        re[r] = c * re[r] + s * pim;
        im[r] = c * im[r] - s * pre;
    }
}

template<int J>
__device__ __forceinline__ void rx_regbit(float (&re)[NR], float (&im)[NR],
                                          float c, float s) {
    #pragma unroll
    for (int r0 = 0; r0 < NR; ++r0) {
        if (r0 & (1 << J)) continue;
        const int r1 = r0 | (1 << J);
        const float R0 = re[r0], M0 = im[r0];
        const float R1 = re[r1], M1 = im[r1];
        re[r0] = c * R0 + s * M1;
        im[r0] = c * M0 - s * R1;
        re[r1] = c * R1 + s * M0;
        im[r1] = c * M1 - s * R0;
    }
}

__device__ __forceinline__ void cnot_ring(float (&re)[NR], float (&im)[NR],
                                          int lane, int jaddr, int addr32) {
    // CNOTs (0->1)...(4->5): composed lane permutation, one bpermute pass
    #pragma unroll
    for (int r = 0; r < NR; ++r) {
        re[r] = xf(__builtin_amdgcn_ds_bpermute(jaddr, fx(re[r])));
        im[r] = xf(__builtin_amdgcn_ds_bpermute(jaddr, fx(im[r])));
    }
    // C(5->6): ctrl lane bit0, tgt reg bit3 -> conditional reg swap
    const bool ctl = (lane & 1) != 0;
    #pragma unroll
    for (int r = 0; r < 8; ++r) {
        const float a0 = re[r], a1 = re[r + 8];
        re[r] = ctl ? a1 : a0;  re[r + 8] = ctl ? a0 : a1;
        const float b0 = im[r], b1 = im[r + 8];
        im[r] = ctl ? b1 : b0;  im[r + 8] = ctl ? b0 : b1;
    }
    // C(6->7): regs bit3=1 swap bit2
    #pragma unroll
    for (int r = 8; r < 12; ++r) {
        float t = re[r]; re[r] = re[r + 4]; re[r + 4] = t;
        t = im[r]; im[r] = im[r + 4]; im[r + 4] = t;
    }
    // C(7->8): regs bit2=1 swap bit1
    {
        const int rs[4] = {4, 5, 12, 13};
        #pragma unroll
        for (int k = 0; k < 4; ++k) {
            const int r = rs[k];
            float t = re[r]; re[r] = re[r + 2]; re[r + 2] = t;
            t = im[r]; im[r] = im[r + 2]; im[r + 2] = t;
        }
    }
    // C(8->9): regs bit1=1 swap bit0
    {
        const int rs[4] = {2, 6, 10, 14};
        #pragma unroll
        for (int k = 0; k < 4; ++k) {
            const int r = rs[k];
            float t = re[r]; re[r] = re[r + 1]; re[r + 1] = t;
            t = im[r]; im[r] = im[r + 1]; im[r + 1] = t;
        }
    }
    // C(9->0): ctrl reg bit0, tgt lane mask 32 -> bpermute odd regs
    #pragma unroll
    for (int r = 1; r < NR; r += 2) {
        re[r] = lane_xor<32>(re[r], addr32);
        im[r] = lane_xor<32>(im[r], addr32);
    }
}

__global__ __launch_bounds__(256, 2) void vql_kernel(
    const float* __restrict__ x,     // (B, NQ)
    const float* __restrict__ w,     // (NDEPTH, NQ)
    float* __restrict__ out,         // (B, NQ)
    int B)
{
    const int lane = threadIdx.x & 63;
    const int b = blockIdx.x * 4 + (threadIdx.x >> 6);
    if (b >= B) return;

    // hoisted cross-lane addresses
    const int addr32 = (lane ^ 32) << 2;
    int j = lane;                       // composed C(0->1)..C(4->5) source lane
    j ^= ((j >> 1) & 1);
    j ^= ((j >> 2) & 1) << 1;
    j ^= ((j >> 3) & 1) << 2;
    j ^= ((j >> 4) & 1) << 3;
    j ^= ((j >> 5) & 1) << 4;
    const int jaddr = j << 2;

    // ---- per-batch angles (vectorized) ----
    const float2* xr = reinterpret_cast<const float2*>(x + b * NQ);
    const float2 x01 = xr[0], x23 = xr[1], x45 = xr[2], x67 = xr[3], x89 = xr[4];
    const float xa[NQ] = {0.5f * x01.x, 0.5f * x01.y, 0.5f * x23.x, 0.5f * x23.y,
                          0.5f * x45.x, 0.5f * x45.y, 0.5f * x67.x, 0.5f * x67.y,
                          0.5f * x89.x, 0.5f * x89.y};

    // ---- per-qubit factors: RX(w0q) RY(xq) |0> = (v0, v1) ----
    float v0r[NQ], v0i[NQ], v1r[NQ], v1i[NQ];
    #pragma unroll
    for (int q = 0; q < NQ; ++q) {
        float sy, cy, s, c;
        __sincosf(xa[q], &sy, &cy);
        __sincosf(0.5f * w[q], &s, &c);   // layer-0 weights
        v0r[q] = c * cy;  v0i[q] = -s * sy;
        v1r[q] = c * sy;  v1i[q] = -s * cy;
    }

    // ---- init = ring-0 applied to the product state, built DIRECTLY ----
    // amp_out[i] = prod_q f_q(bit_q(j(i))),  j = (i ^ (i>>1)) ^ ((i&1)*0x300)
    // With i = lane*16 + r (lane bits L5..L0, reg bits r3..r0):
    //   q0: L5^r0   q1: L4^L5^r0   q2: L3^L4   q3: L2^L3   q4: L1^L2
    //   q5: L0^L1   q6: r3^L0      q7: r2^r3   q8: r1^r2   q9: r0^r1
    const int L0 = lane & 1,        L1 = (lane >> 1) & 1, L2 = (lane >> 2) & 1;
    const int L3 = (lane >> 3) & 1, L4 = (lane >> 4) & 1, L5 = (lane >> 5) & 1;
    #define FR_(q,bit) ((bit) ? v1r[q] : v0r[q])
    #define FI_(q,bit) ((bit) ? v1i[q] : v0i[q])

    float Plr, Pli;     // f2*f3*f4*f5 (lane-only)
    {
        const int i2 = L3 ^ L4, i3 = L2 ^ L3, i4 = L1 ^ L2, i5 = L0 ^ L1;
        const float t1r = FR_(2,i2) * FR_(3,i3) - FI_(2,i2) * FI_(3,i3);
        const float t1i = FR_(2,i2) * FI_(3,i3) + FI_(2,i2) * FR_(3,i3);
        const float t2r = FR_(4,i4) * FR_(5,i5) - FI_(4,i4) * FI_(5,i5);
        const float t2i = FR_(4,i4) * FI_(5,i5) + FI_(4,i4) * FR_(5,i5);
        Plr = t1r * t2r - t1i * t2i;
        Pli = t1r * t2i + t1i * t2r;
    }
    float Ar[2], Ai[2];  // P_lane * f0(L5^r0) * f1(L4^L5^r0)
    #pragma unroll
    for (int r0 = 0; r0 < 2; ++r0) {
        const int i0 = L5 ^ r0, i1 = L4 ^ L5 ^ r0;
        const float ur = FR_(0,i0) * FR_(1,i1) - FI_(0,i0) * FI_(1,i1);
        const float ui = FR_(0,i0) * FI_(1,i1) + FI_(0,i0) * FR_(1,i1);
        Ar[r0] = Plr * ur - Pli * ui;
        Ai[r0] = Plr * ui + Pli * ur;
    }
    float Dr[2][2], Di[2][2];  // f6(r3^L0) * f7(r2^r3)
    #pragma unroll
    for (int r3 = 0; r3 < 2; ++r3)
        #pragma unroll
        for (int r2 = 0; r2 < 2; ++r2) {
            const int i6 = r3 ^ L0, i7 = r2 ^ r3;
            Dr[r3][r2] = FR_(6,i6) * FR_(7,i7) - FI_(6,i6) * FI_(7,i7);
            Di[r3][r2] = FR_(6,i6) * FI_(7,i7) + FI_(6,i6) * FR_(7,i7);
        }
    float Er[2][2], Ei[2][2];  // f8(a) * f9(bb)
    #pragma unroll
    for (int a = 0; a < 2; ++a)
        #pragma unroll
        for (int bb = 0; bb < 2; ++bb) {
            Er[a][bb] = FR_(8,a) * FR_(9,bb) - FI_(8,a) * FI_(9,bb);
            Ei[a][bb] = FR_(8,a) * FI_(9,bb) + FI_(8,a) * FR_(9,bb);
        }
    float re[NR], im[NR];
    #pragma unroll
    for (int r = 0; r < NR; ++r) {
        const int r3 = (r >> 3) & 1, r2 = (r >> 2) & 1, r1 = (r >> 1) & 1, r0 = r & 1;
        const float dr = Dr[r3][r2], di = Di[r3][r2];
        const float er = Er[r1 ^ r2][r0 ^ r1], ei = Ei[r1 ^ r2][r0 ^ r1];
        const float gr = dr * er - di * ei;
        const float gi = dr * ei + di * er;
        re[r] = Ar[r0] * gr - Ai[r0] * gi;
        im[r] = Ar[r0] * gi + Ai[r0] * gr;
    }
    #undef FR_
    #undef FI_

    // ---- layers 1..3: RX all qubits; ring only after layers 1,2 ----
    #pragma unroll
    for (int l = 1; l < NDEPTH; ++l) {
        float c[NQ], s[NQ];
        #pragma unroll
        for (int q = 0; q < NQ; ++q)
            __sincosf(0.5f * w[l * NQ + q], &s[q], &c[q]);
        rx_lanebit<32>(re, im, c[0], s[0], addr32);
        rx_lanebit<16>(re, im, c[1], s[1], addr32);
        rx_lanebit< 8>(re, im, c[2], s[2], addr32);
        rx_lanebit< 4>(re, im, c[3], s[3], addr32);
        rx_lanebit< 2>(re, im, c[4], s[4], addr32);
        rx_lanebit< 1>(re, im, c[5], s[5], addr32);
        rx_regbit<3>(re, im, c[6], s[6]);
        rx_regbit<2>(re, im, c[7], s[7]);
        rx_regbit<1>(re, im, c[8], s[8]);
        rx_regbit<0>(re, im, c[9], s[9]);
        if (l < NDEPTH - 1)
            cnot_ring(re, im, lane, jaddr, addr32);
    }

    // ---- readout: ring-3 pushed through -> parity-mask observables ----
    // z0 = <Z1..Z9>: lane mask 0x1F, reg mask 0xF
    // zq (q>=1) = <Z0..Zq>: q<=5: lane mask = bits 5..(5-q); q>=6: lane 0x3F,
    //             reg mask = bits 3..(9-q)
    float p[NR];
    #pragma unroll
    for (int r = 0; r < NR; ++r) p[r] = re[r] * re[r] + im[r] * im[r];

    float S0 = 0.f, S8 = 0.f, SC = 0.f, SE = 0.f, SF = 0.f;
    #pragma unroll
    for (int r = 0; r < NR; ++r) {
        const int b3 = (r >> 3) & 1, b2 = (r >> 2) & 1, b1 = (r >> 1) & 1, b0 = r & 1;
        S0 += p[r];
        S8 += (b3)                ? -p[r] : p[r];
        SC += (b3 ^ b2)           ? -p[r] : p[r];
        SE += (b3 ^ b2 ^ b1)      ? -p[r] : p[r];
        SF += (b3 ^ b2 ^ b1 ^ b0) ? -p[r] : p[r];
    }
    const float sg1F = (__builtin_popcount(lane & 0x1F) & 1) ? -1.f : 1.f;
    const float sg30 = (__builtin_popcount(lane & 0x30) & 1) ? -1.f : 1.f;
    const float sg38 = (__builtin_popcount(lane & 0x38) & 1) ? -1.f : 1.f;
    const float sg3C = (__builtin_popcount(lane & 0x3C) & 1) ? -1.f : 1.f;
    const float sg3E = (__builtin_popcount(lane & 0x3E) & 1) ? -1.f : 1.f;
    const float sg3F = (__builtin_popcount(lane & 0x3F) & 1) ? -1.f : 1.f;

    float z[NQ];
    z[0] = sg1F * SF;
    z[1] = sg30 * S0;
    z[2] = sg38 * S0;
    z[3] = sg3C * S0;
    z[4] = sg3E * S0;
    z[5] = sg3F * S0;
    z[6] = sg3F * S8;
    z[7] = sg3F * SC;
    z[8] = sg3F * SE;
    z[9] = sg3F * SF;

    #pragma unroll
    for (int q = 0; q < NQ; ++q) {
        z[q] += lane_xor<1>(z[q], addr32);
        z[q] += lane_xor<2>(z[q], addr32);
        z[q] += lane_xor<4>(z[q], addr32);
        z[q] += lane_xor<8>(z[q], addr32);
        z[q] += lane_xor<16>(z[q], addr32);
        z[q] += lane_xor<32>(z[q], addr32);
    }
    if (lane == 0) {
        #pragma unroll
        for (int q = 0; q < NQ; ++q) out[b * NQ + q] = z[q];
    }
}

extern "C" void kernel_launch(void* const* d_in, const int* in_sizes, int n_in,
                              void* d_out, int out_size, void* d_ws, size_t ws_size,
                              hipStream_t stream) {
    const float* x = (const float*)d_in[0];        // (BATCH, NQ) fp32
    const float* w = (const float*)d_in[1];        // (NDEPTH, NQ) fp32
    float* out = (float*)d_out;                    // (BATCH, NQ) fp32
    const int B = in_sizes[0] / NQ;
    vql_kernel<<<(B + 3) / 4, 256, 0, stream>>>(x, w, out, B);
}